// Round 1
// baseline (113.702 us; speedup 1.0000x reference)
//
#include <hip/hip_runtime.h>

// RoiDeform: inputs (2,1600,1600,3) f32, delta_p (2,4,4,2) f32, k=4, cs=384.
// out[b,bin,r,s,c] = bilinear(img_b, 32 + (bin/4)*384 + s + dp0, 32 + (bin%4)*384 + s + dp1)[c]
//   -- independent of r (broadcast along r). Pure store-BW problem (56.6 MB out).

constexpr int B  = 2;
constexpr int H  = 1600;
constexpr int W  = 1600;
constexpr int C  = 3;
constexpr int K  = 4;
constexpr int CS = 384;
constexpr int PL = (H - CS * K) / 2;      // 32
constexpr int ROW_F  = CS * C;            // 1152 floats per output row
constexpr int ROW_F4 = ROW_F / 4;         // 288 float4 per output row
constexpr int RCHUNK = 8;                 // output rows written per block
constexpr int NCHUNK = CS / RCHUNK;       // 48 chunks per (b,bin)
constexpr int CHUNK_F4 = RCHUNK * ROW_F4; // 2304 float4 per block

__global__ __launch_bounds__(256) void roideform_kernel(
    const float* __restrict__ img,   // (B,H,W,C)
    const float* __restrict__ dp,    // (B,K,K,2)
    float* __restrict__ out)         // (B,K*K,CS,CS,C)
{
    const int bid    = blockIdx.x;
    const int bbin   = bid / NCHUNK;          // b*16 + bin
    const int rchunk = bid - bbin * NCHUNK;
    const int b      = bbin >> 4;
    const int bin    = bbin & 15;
    const int i      = bin >> 2;
    const int j      = bin & 3;

    __shared__ float vrow[ROW_F];

    const float dp0 = dp[((b * K + i) * K + j) * 2 + 0];
    const float dp1 = dp[((b * K + i) * K + j) * 2 + 1];
    const float* __restrict__ imgb = img + (size_t)b * H * W * C;

    // Phase 1: 384 diagonal bilinear samples -> LDS (s-major, c-minor)
    for (int s = threadIdx.x; s < CS; s += blockDim.x) {
        const float r = (float)(PL + i * CS + s) + dp0;
        const float c = (float)(PL + j * CS + s) + dp1;
        const float r0 = floorf(r), c0 = floorf(c);
        const float rf = r - r0,   cf = c - c0;
        const int ri0 = (int)r0, ci0 = (int)c0;

        float acc0 = 0.f, acc1 = 0.f, acc2 = 0.f;
#pragma unroll
        for (int dr = 0; dr < 2; ++dr) {
            const int  ri = ri0 + dr;
            const float wr = dr ? rf : (1.0f - rf);
            const bool rvalid = (ri >= 0) && (ri < H);
#pragma unroll
            for (int dc = 0; dc < 2; ++dc) {
                const int  ci = ci0 + dc;
                const float wc = dc ? cf : (1.0f - cf);
                if (rvalid && (ci >= 0) && (ci < W)) {
                    const float w = wr * wc;
                    const float* p = imgb + ((size_t)ri * W + ci) * C;
                    acc0 += w * p[0];
                    acc1 += w * p[1];
                    acc2 += w * p[2];
                }
            }
        }
        vrow[s * 3 + 0] = acc0;
        vrow[s * 3 + 1] = acc1;
        vrow[s * 3 + 2] = acc2;
    }
    __syncthreads();

    // Phase 2: broadcast-write RCHUNK identical rows, coalesced float4.
    const float4* __restrict__ v4 = (const float4*)vrow;
    float4* __restrict__ out4 =
        (float4*)out + (size_t)(bbin * CS + rchunk * RCHUNK) * ROW_F4;

    for (int t = threadIdx.x; t < CHUNK_F4; t += 256) {
        out4[t] = v4[t % ROW_F4];
    }
}

extern "C" void kernel_launch(void* const* d_in, const int* in_sizes, int n_in,
                              void* d_out, int out_size, void* d_ws, size_t ws_size,
                              hipStream_t stream) {
    const float* img = (const float*)d_in[0];
    const float* dp  = (const float*)d_in[1];
    float* out = (float*)d_out;

    const int grid = B * K * K * NCHUNK;   // 1536 blocks
    roideform_kernel<<<grid, 256, 0, stream>>>(img, dp, out);
}

// Round 2
// 106.520 us; speedup vs baseline: 1.0674x; 1.0674x over previous
//
#include <hip/hip_runtime.h>

// RoiDeform: inputs (2,1600,1600,3) f32, delta_p (2,4,4,2) f32, k=4, cs=384.
// out[b,bin,r,s,c] = bilinear(img_b, 32 + (bin/4)*384 + s + dp0, 32 + (bin%4)*384 + s + dp1)[c]
//   -- independent of r (broadcast along r). Two-kernel split:
//   K1: 32 unique sample rows (12,288 bilinear gathers) -> d_ws (590 KB), done ONCE
//   K2: pure broadcast-store of 56.6 MB output, reading rows from ws via LDS.

constexpr int B  = 2;
constexpr int H  = 1600;
constexpr int W  = 1600;
constexpr int C  = 3;
constexpr int K  = 4;
constexpr int CS = 384;
constexpr int PL = (H - CS * K) / 2;      // 32
constexpr int ROW_F  = CS * C;            // 1152 floats per sample row
constexpr int ROW_F4 = ROW_F / 4;         // 288 float4 per sample row
constexpr int NBBIN  = B * K * K;         // 32 (b,bin) pairs
constexpr int RCHUNK = 8;                 // output rows written per K2 block
constexpr int NCHUNK = CS / RCHUNK;       // 48 chunks per (b,bin)
constexpr int K2_ITERS = RCHUNK * ROW_F4 / 256;  // 9 float4 stores per thread

// ---------------- K1: gather 32 sample rows into ws ----------------
// grid = NBBIN * 3 blocks, block = 128 threads; thread -> one sample s.
__global__ __launch_bounds__(128) void roideform_gather(
    const float* __restrict__ img,   // (B,H,W,C)
    const float* __restrict__ dp,    // (B,K,K,2)
    float* __restrict__ ws)          // (NBBIN, CS, C)
{
    const int bbin = blockIdx.x / 3;
    const int s    = (blockIdx.x % 3) * 128 + threadIdx.x;
    const int b    = bbin >> 4;
    const int bin  = bbin & 15;
    const int i    = bin >> 2;
    const int j    = bin & 3;

    const float dp0 = dp[((b * K + i) * K + j) * 2 + 0];
    const float dp1 = dp[((b * K + i) * K + j) * 2 + 1];
    const float* __restrict__ imgb = img + (size_t)b * H * W * C;

    const float r = (float)(PL + i * CS + s) + dp0;
    const float c = (float)(PL + j * CS + s) + dp1;
    const float r0 = floorf(r), c0 = floorf(c);
    const float rf = r - r0,   cf = c - c0;
    const int ri0 = (int)r0, ci0 = (int)c0;

    float acc0 = 0.f, acc1 = 0.f, acc2 = 0.f;
#pragma unroll
    for (int dr = 0; dr < 2; ++dr) {
        const int  ri = ri0 + dr;
        const float wr = dr ? rf : (1.0f - rf);
        const bool rvalid = (ri >= 0) && (ri < H);
#pragma unroll
        for (int dc = 0; dc < 2; ++dc) {
            const int  ci = ci0 + dc;
            const float wc = dc ? cf : (1.0f - cf);
            if (rvalid && (ci >= 0) && (ci < W)) {
                const float w = wr * wc;
                const float* p = imgb + ((size_t)ri * W + ci) * C;
                acc0 += w * p[0];
                acc1 += w * p[1];
                acc2 += w * p[2];
            }
        }
    }
    float* o = ws + ((size_t)bbin * CS + s) * C;
    o[0] = acc0;
    o[1] = acc1;
    o[2] = acc2;
}

// ---------------- K2: broadcast-store ----------------
// grid = NBBIN * NCHUNK = 1536 blocks, block = 256 threads.
__global__ __launch_bounds__(256) void roideform_bcast(
    const float* __restrict__ ws,    // (NBBIN, CS, C)
    float* __restrict__ out)         // (B, K*K, CS, CS, C)
{
    const int bid   = blockIdx.x;
    const int bbin  = bid / NCHUNK;
    const int chunk = bid - bbin * NCHUNK;

    __shared__ float4 row[ROW_F4];
    const float4* __restrict__ ws4 = (const float4*)ws + (size_t)bbin * ROW_F4;
    for (int t = threadIdx.x; t < ROW_F4; t += 256) row[t] = ws4[t];
    __syncthreads();

    float4* __restrict__ out4 =
        (float4*)out + (size_t)(bbin * CS + chunk * RCHUNK) * ROW_F4;

#pragma unroll
    for (int it = 0; it < K2_ITERS; ++it) {
        const int t = it * 256 + (int)threadIdx.x;
        out4[t] = row[t % ROW_F4];
    }
}

extern "C" void kernel_launch(void* const* d_in, const int* in_sizes, int n_in,
                              void* d_out, int out_size, void* d_ws, size_t ws_size,
                              hipStream_t stream) {
    const float* img = (const float*)d_in[0];
    const float* dp  = (const float*)d_in[1];
    float* out = (float*)d_out;
    float* ws  = (float*)d_ws;

    roideform_gather<<<NBBIN * 3, 128, 0, stream>>>(img, dp, ws);
    roideform_bcast<<<NBBIN * NCHUNK, 256, 0, stream>>>(ws, out);
}